// Round 8
// baseline (313.827 us; speedup 1.0000x reference)
//
#include <hip/hip_runtime.h>
#include <hip/hip_bf16.h>

// QDense: out = s * (U X U^H)[:128,:128] / tr + (1-s) * diag(softmax(rand_w))
// B=512, D=256, O=128.
// Round-8: r3 dataflow, X global->reg DIRECT (wave-private, MFMA fragment
// order) with explicit 2-deep/3-slot register pipeline; no X LDS, no
// per-phase barriers.  LDS = U-half 64KB + Yt 16KB = 80KB -> 2 blocks/CU.
// Raw s_barrier + lgkmcnt(0) only (vmcnt stays counted across barriers).
// 1024 blocks (b = bx>>1, k'-half kh = bx&1), 512 thr.
// Trace via Q = (U_sub^H U_sub)^T folded into stage A on waves 0..3.

typedef __attribute__((ext_vector_type(4))) float f32x4;
typedef __attribute__((ext_vector_type(8))) short bf16x8;

static __device__ __forceinline__ short f2bf(float f) {   // prep kernels only
    unsigned u = __float_as_uint(f);
    u += 0x7fffu + ((u >> 16) & 1u);
    return (short)(u >> 16);
}

static __device__ __forceinline__ unsigned cvtpk2(float lo, float hi) {
    union { __hip_bfloat162 h; unsigned u; } c;
    c.h = __float22bfloat162_rn(float2{lo, hi});
    return c.u;
}

static __device__ __forceinline__ bf16x8 pack8(f32x4 a, f32x4 b) {
    union { unsigned u[4]; bf16x8 v; } r;
    r.u[0] = cvtpk2(a[0], a[1]);
    r.u[1] = cvtpk2(a[2], a[3]);
    r.u[2] = cvtpk2(b[0], b[1]);
    r.u[3] = cvtpk2(b[2], b[3]);
    return r.v;
}

static __device__ __forceinline__ f32x4 mfma16(bf16x8 a, bf16x8 b, f32x4 c) {
    return __builtin_amdgcn_mfma_f32_16x16x32_bf16(a, b, c, 0, 0, 0);
}

// slice S = (jt = S>>3, ks = S&7): offset from per-lane base, in floats
// (X) or shorts (Q): jt*256*... -> (S>>3)*64rows*256 + (S&7)*32
#define XGOFF(S) (((S) >> 3) * 16384 + ((S) & 7) * 32)

// ---- prep kernels (r3 verbatim) ----
__global__ void qprep_u(const float* __restrict__ wt,
                        short* __restrict__ Ur, short* __restrict__ Ui) {
    int idx = blockIdx.x * 256 + threadIdx.x;
    float2 v = ((const float2*)wt)[idx];
    Ur[idx] = f2bf(v.x);
    Ui[idx] = f2bf(v.y);
}

__global__ void qprep_ps(const float* __restrict__ rw, const float* __restrict__ lm,
                         float* __restrict__ pv, float* __restrict__ sv) {
    int t = threadIdx.x;
    float w0 = rw[t], w1 = rw[t + 64];
    float m = fmaxf(w0, w1);
    #pragma unroll
    for (int o = 32; o > 0; o >>= 1) m = fmaxf(m, __shfl_xor(m, o));
    float e0 = expf(w0 - m), e1 = expf(w1 - m);
    float ss = e0 + e1;
    #pragma unroll
    for (int o = 32; o > 0; o >>= 1) ss += __shfl_xor(ss, o);
    pv[t] = e0 / ss;
    pv[t + 64] = e1 / ss;
    if (t == 0) sv[0] = 1.f / (1.f + expf(-lm[0]));
}

__global__ void qprep_q(const float* __restrict__ wt,
                        short* __restrict__ Qrb, short* __restrict__ Qib) {
    int j = blockIdx.x;
    int k = threadIdx.x;
    float ar = 0.f, ai = 0.f;
    for (int i = 0; i < 128; ++i) {
        float2 uk = ((const float2*)wt)[i * 256 + k];
        float2 uj = ((const float2*)wt)[i * 256 + j];
        ar += uk.x * uj.x + uk.y * uj.y;
        ai += uk.x * uj.y - uk.y * uj.x;
    }
    Qrb[j * 256 + k] = f2bf(ar);
    Qib[j * 256 + k] = f2bf(ai);
}

// ---- one pipeline phase (P = 0..31 compile-time) ----
template<int P>
static __device__ __forceinline__ void phaseT(
    const char* smem, const float* xgR, const float* xgI,
    const short* qbr, const short* qbi,
    int kb, int c16, int g4, bool dotr,
    f32x4* gRa, f32x4* gRb, f32x4* gIa, f32x4* gIb,
    bf16x8* qgr, bf16x8* qgi,
    f32x4* yR, f32x4* yI, f32x4& tr4)
{
    // 1. issue global loads for slice P+2 into ring slot (P+2)%3
    if (P + 2 < 32) {
        constexpr int S = (P + 2 < 32) ? P + 2 : 0;
        gRa[S % 3] = *(const f32x4*)(xgR + XGOFF(S));
        gRb[S % 3] = *(const f32x4*)(xgR + XGOFF(S) + 4);
        gIa[S % 3] = *(const f32x4*)(xgI + XGOFF(S));
        gIb[S % 3] = *(const f32x4*)(xgI + XGOFF(S) + 4);
    }
    // 2. Q prefetch slice P+1 (2-slot ring)
    if (dotr && (P + 1 < 32)) {
        qgr[(P + 1) & 1] = *(const bf16x8*)(qbr + XGOFF(P + 1));
        qgi[(P + 1) & 1] = *(const bf16x8*)(qbi + XGOFF(P + 1));
    }
    asm volatile("" ::: "memory");   // pin issued loads above this point
    // 3. consume slice P from ring slot P%3 (compiler emits counted vmcnt)
    bf16x8 axr  = pack8(gRa[P % 3], gRb[P % 3]);
    bf16x8 axi  = pack8(gIa[P % 3], gIb[P % 3]);
    bf16x8 axrn = axr ^ (short)0x8000;
    {
        const int kloc = kb + c16;
        const int uo = kloc * 512 + (((P & 7) * 64 + g4 * 16) ^ ((kloc & 7) << 4));
        bf16x8 bur = *(const bf16x8*)(smem + uo);
        bf16x8 bui = *(const bf16x8*)(smem + 32768 + uo);
        // Yr = Xr Ur^T + Xi Ui^T ; Yi = Xi Ur^T - Xr Ui^T
        yR[0] = mfma16(axr,  bur, yR[0]);
        yR[0] = mfma16(axi,  bui, yR[0]);
        yI[0] = mfma16(axi,  bur, yI[0]);
        yI[0] = mfma16(axrn, bui, yI[0]);
    }
    {
        const int kloc = kb + 16 + c16;
        const int uo = kloc * 512 + (((P & 7) * 64 + g4 * 16) ^ ((kloc & 7) << 4));
        bf16x8 bur = *(const bf16x8*)(smem + uo);
        bf16x8 bui = *(const bf16x8*)(smem + 32768 + uo);
        yR[1] = mfma16(axr,  bur, yR[1]);
        yR[1] = mfma16(axi,  bui, yR[1]);
        yI[1] = mfma16(axi,  bur, yI[1]);
        yI[1] = mfma16(axrn, bui, yI[1]);
    }
    if (dotr) {
        bf16x8 axin = axi ^ (short)0x8000;
        tr4 = mfma16(axr,  qgr[P & 1], tr4);
        tr4 = mfma16(axin, qgi[P & 1], tr4);
    }
}

// ---- stage B compute for one jt (Yt at 65536/73728) ----
static __device__ __forceinline__ void stageB(
    const char* smem, const short* Urg, const short* Uig, int jt,
    int wm, int wn, int c16, int g4,
    f32x4 (&sR)[2][2], f32x4 (&sI)[2][2])
{
    #pragma unroll
    for (int ks2 = 0; ks2 < 2; ++ks2) {
        bf16x8 aur[2], aui[2], auin[2];
        #pragma unroll
        for (int mt = 0; mt < 2; ++mt) {
            int i = wm * 32 + mt * 16 + c16;
            aur[mt]  = *(const bf16x8*)(Urg + (size_t)i * 256 + jt + ks2 * 32 + g4 * 8);
            aui[mt]  = *(const bf16x8*)(Uig + (size_t)i * 256 + jt + ks2 * 32 + g4 * 8);
            auin[mt] = aui[mt] ^ (short)0x8000;
        }
        #pragma unroll
        for (int nt2 = 0; nt2 < 2; ++nt2) {
            int kloc = wn * 32 + nt2 * 16 + c16;
            int off  = kloc * 128 + ((ks2 * 64 + g4 * 16) ^ ((kloc & 7) << 4));
            bf16x8 byr = *(const bf16x8*)(smem + 65536 + off);
            bf16x8 byi = *(const bf16x8*)(smem + 73728 + off);
            #pragma unroll
            for (int mt = 0; mt < 2; ++mt) {
                sR[mt][nt2] = mfma16(aur[mt],  byr, sR[mt][nt2]);
                sR[mt][nt2] = mfma16(auin[mt], byi, sR[mt][nt2]);
                sI[mt][nt2] = mfma16(aui[mt],  byr, sI[mt][nt2]);
                sI[mt][nt2] = mfma16(aur[mt],  byi, sI[mt][nt2]);
            }
        }
    }
}

// ---- Yt exchange + stage B ----
// barrier1: all waves done READING Yt(prev stageB) -> safe to overwrite.
// barrier2: all Yt writes visible -> safe to read.
#define YT_AND_B(JT) do {                                                       \
    __builtin_amdgcn_s_barrier();                                               \
    __builtin_amdgcn_sched_barrier(0);                                          \
    {                                                                           \
        const int klA = kb + c16;                                               \
        const int oA  = klA * 128 + ((ja * 2 + g4 * 8) ^ ((klA & 7) << 4));     \
        uint2 v;                                                                \
        v.x = cvtpk2(yR[0][0], yR[0][1]); v.y = cvtpk2(yR[0][2], yR[0][3]);     \
        *(uint2*)(smem + 65536 + oA) = v;                                       \
        v.x = cvtpk2(yI[0][0], yI[0][1]); v.y = cvtpk2(yI[0][2], yI[0][3]);     \
        *(uint2*)(smem + 73728 + oA) = v;                                       \
        const int klB = kb + 16 + c16;                                          \
        const int oB  = klB * 128 + ((ja * 2 + g4 * 8) ^ ((klB & 7) << 4));     \
        v.x = cvtpk2(yR[1][0], yR[1][1]); v.y = cvtpk2(yR[1][2], yR[1][3]);     \
        *(uint2*)(smem + 65536 + oB) = v;                                       \
        v.x = cvtpk2(yI[1][0], yI[1][1]); v.y = cvtpk2(yI[1][2], yI[1][3]);     \
        *(uint2*)(smem + 73728 + oB) = v;                                       \
    }                                                                           \
    asm volatile("s_waitcnt lgkmcnt(0)" ::: "memory");                          \
    __builtin_amdgcn_sched_barrier(0);                                          \
    __builtin_amdgcn_s_barrier();                                               \
    __builtin_amdgcn_sched_barrier(0);                                          \
    stageB(smem, Urg, Uig, (JT) * 64, wm, wn, c16, g4, sR, sI);                 \
    yR[0] = zero; yR[1] = zero; yI[0] = zero; yI[1] = zero;                     \
} while (0)

#define PH(P) phaseT<P>(smem, xgR, xgI, qbr, qbi, kb, c16, g4, dotr,            \
                        gRa, gRb, gIa, gIb, qgr, qgi, yR, yI, tr4)

// ---- main fused kernel ----
__global__ __launch_bounds__(512, 4) void qfused(
    const float* __restrict__ xr, const float* __restrict__ xi,
    const short* __restrict__ Urg, const short* __restrict__ Uig,
    const short* __restrict__ Qrb, const short* __restrict__ Qib,
    const float* __restrict__ pv, const float* __restrict__ sv,
    float* __restrict__ out)
{
    // LDS: [0,65536) U-half swizzled (R 0, I 32768); [65536,81920) Yt (R/I).
    __shared__ __align__(16) char smem[81920];

    const int bx   = blockIdx.x;
    const int b    = bx >> 1;
    const int kh   = bx & 1;
    const int tid  = threadIdx.x;
    const int lane = tid & 63;
    const int w    = tid >> 6;
    const int c16  = lane & 15;
    const int g4   = lane >> 4;

    // ---- stage U-half into swizzled LDS (r3-proven) ----
    #pragma unroll
    for (int q = 0; q < 4; ++q) {
        int c    = tid + q * 512;
        int row  = c >> 5;
        int slot = c & 31;
        int ss   = slot ^ (row & 7);
        const short* sr = Urg + (size_t)(kh * 64 + row) * 256 + ss * 8;
        const short* si = Uig + (size_t)(kh * 64 + row) * 256 + ss * 8;
        *(bf16x8*)(smem + row * 512 + slot * 16)         = *(const bf16x8*)sr;
        *(bf16x8*)(smem + 32768 + row * 512 + slot * 16) = *(const bf16x8*)si;
    }

    const float* xrb = xr + ((size_t)b << 16);
    const float* xib = xi + ((size_t)b << 16);

    const int  ja   = (w & 3) * 16;      // stage-A j-group
    const int  kb   = (w >> 2) * 32;     // stage-A k'-group
    const int  wm   = w >> 1;            // stage-B i-quarter
    const int  wn   = w & 1;             // stage-B k'-half-of-half
    const bool dotr = (w < 4);

    // per-lane X/Q base (fragment order: row ja+c16, k chunk g4*8)
    const float* xgR = xrb + (size_t)(ja + c16) * 256 + g4 * 8;
    const float* xgI = xib + (size_t)(ja + c16) * 256 + g4 * 8;
    const short* qbr = Qrb + (size_t)(ja + c16) * 256 + g4 * 8;
    const short* qbi = Qib + (size_t)(ja + c16) * 256 + g4 * 8;

    f32x4 zero = {0.f, 0.f, 0.f, 0.f};
    f32x4 sR[2][2], sI[2][2];
    #pragma unroll
    for (int m = 0; m < 2; ++m)
        #pragma unroll
        for (int n = 0; n < 2; ++n) { sR[m][n] = zero; sI[m][n] = zero; }
    f32x4 tr4 = zero;
    f32x4 yR[2], yI[2];
    yR[0] = zero; yR[1] = zero; yI[0] = zero; yI[1] = zero;

    f32x4 gRa[3], gRb[3], gIa[3], gIb[3];
    bf16x8 qgr[2], qgi[2];

    // ---- prologue: issue slices 0,1 + Q slice 0 ----
    gRa[0] = *(const f32x4*)(xgR + XGOFF(0));
    gRb[0] = *(const f32x4*)(xgR + XGOFF(0) + 4);
    gIa[0] = *(const f32x4*)(xgI + XGOFF(0));
    gIb[0] = *(const f32x4*)(xgI + XGOFF(0) + 4);
    gRa[1] = *(const f32x4*)(xgR + XGOFF(1));
    gRb[1] = *(const f32x4*)(xgR + XGOFF(1) + 4);
    gIa[1] = *(const f32x4*)(xgI + XGOFF(1));
    gIb[1] = *(const f32x4*)(xgI + XGOFF(1) + 4);
    if (dotr) {
        qgr[0] = *(const bf16x8*)(qbr + XGOFF(0));
        qgi[0] = *(const bf16x8*)(qbi + XGOFF(0));
    }
    asm volatile("s_waitcnt lgkmcnt(0)" ::: "memory");   // U staging visible
    __builtin_amdgcn_sched_barrier(0);
    __builtin_amdgcn_s_barrier();                        // vmcnt stays counted
    __builtin_amdgcn_sched_barrier(0);

    PH(0);  PH(1);  PH(2);  PH(3);  PH(4);  PH(5);  PH(6);  PH(7);
    YT_AND_B(0);
    PH(8);  PH(9);  PH(10); PH(11); PH(12); PH(13); PH(14); PH(15);
    YT_AND_B(1);
    PH(16); PH(17); PH(18); PH(19); PH(20); PH(21); PH(22); PH(23);
    YT_AND_B(2);
    PH(24); PH(25); PH(26); PH(27); PH(28); PH(29); PH(30); PH(31);
    YT_AND_B(3);

    // ---- trace: extract diag of tr4, reduce over block ----
    float loc = (dotr && ((c16 >> 2) == g4)) ? tr4[c16 & 3] : 0.f;
    #pragma unroll
    for (int o = 32; o > 0; o >>= 1) loc += __shfl_xor(loc, o);
    __syncthreads();                      // Yt dead; reuse for reduction
    float* red = (float*)(smem + 65536);
    if (lane == 0) red[w] = loc;
    __syncthreads();
    float tr = red[0] + red[1] + red[2] + red[3] + red[4] + red[5] + red[6] + red[7];

    float s     = sv[0];
    float inv   = s / tr;
    float onems = 1.f - s;
    float* outr = out + (size_t)b * 16384;
    float* outi = out + 8388608 + (size_t)b * 16384;

    #pragma unroll
    for (int mt = 0; mt < 2; ++mt)
        #pragma unroll
        for (int nt2 = 0; nt2 < 2; ++nt2) {
            int colc = kh * 64 + wn * 32 + nt2 * 16 + c16;
            #pragma unroll
            for (int r = 0; r < 4; ++r) {
                int row = wm * 32 + mt * 16 + g4 * 4 + r;
                float vr = sR[mt][nt2][r] * inv;
                if (row == colc) vr += onems * pv[row];
                outr[row * 128 + colc] = vr;
                outi[row * 128 + colc] = sI[mt][nt2][r] * inv;
            }
        }
}

extern "C" void kernel_launch(void* const* d_in, const int* in_sizes, int n_in,
                              void* d_out, int out_size, void* d_ws, size_t ws_size,
                              hipStream_t stream) {
    (void)in_sizes; (void)n_in; (void)out_size; (void)ws_size;
    const float* xr = (const float*)d_in[0];
    const float* xi = (const float*)d_in[1];
    const float* wt = (const float*)d_in[2];
    const float* rw = (const float*)d_in[3];
    const float* lm = (const float*)d_in[4];

    short* Ur  = (short*)d_ws;                        // 128x256 bf16 (64 KB)
    short* Ui  = Ur + 32768;                          // 64 KB
    float* pv  = (float*)((char*)d_ws + 131072);      // 128 f32
    float* sv  = pv + 128;                            // 1 f32
    short* Qrb = (short*)((char*)d_ws + 135168);      // 256x256 bf16 (128 KB)
    short* Qib = (short*)((char*)d_ws + 266240);      // 128 KB
    float* o   = (float*)d_out;

    qprep_u<<<dim3(128), dim3(256), 0, stream>>>(wt, Ur, Ui);
    qprep_ps<<<dim3(1), dim3(64), 0, stream>>>(rw, lm, pv, sv);
    qprep_q<<<dim3(256), dim3(256), 0, stream>>>(wt, Qrb, Qib);
    qfused<<<dim3(1024), dim3(512), 0, stream>>>(xr, xi, Ur, Ui, Qrb, Qib, pv, sv, o);
}

// Round 9
// 220.843 us; speedup vs baseline: 1.4210x; 1.4210x over previous
//
#include <hip/hip_runtime.h>
#include <hip/hip_bf16.h>

// QDense: out = s * (U X U^H)[:128,:128] / tr + (1-s) * diag(softmax(rand_w))
// B=512, D=256, O=128.
// Round-9 = round-8 dataflow with the spill fixed: ALL pipeline state in
// named scalar registers (no arrays -> no alloca -> no scratch), phases
// as preprocessor macros over literal P, 2-slot X ring, launch_bounds(512,2).
// X: global->reg direct (wave-private fragment order), 2-deep prefetch.
// U-half: swizzled LDS (64 KB).  Yt: 16 KB LDS.  Total 80 KB -> 2 blocks/CU.
// Barriers: raw s_barrier + lgkmcnt(0) only (vmcnt stays counted across them).
// 1024 blocks (b = bx>>1, k'-half kh = bx&1), 512 thr.
// Trace via Q = (U_sub^H U_sub)^T folded into stage A on waves 0..3.

typedef __attribute__((ext_vector_type(4))) float f32x4;
typedef __attribute__((ext_vector_type(8))) short bf16x8;

static __device__ __forceinline__ short f2bf(float f) {   // prep kernels only
    unsigned u = __float_as_uint(f);
    u += 0x7fffu + ((u >> 16) & 1u);
    return (short)(u >> 16);
}

static __device__ __forceinline__ unsigned cvtpk2(float lo, float hi) {
    union { __hip_bfloat162 h; unsigned u; } c;
    c.h = __float22bfloat162_rn(float2{lo, hi});
    return c.u;
}

static __device__ __forceinline__ bf16x8 pack8(f32x4 a, f32x4 b) {
    union { unsigned u[4]; bf16x8 v; } r;
    r.u[0] = cvtpk2(a[0], a[1]);
    r.u[1] = cvtpk2(a[2], a[3]);
    r.u[2] = cvtpk2(b[0], b[1]);
    r.u[3] = cvtpk2(b[2], b[3]);
    return r.v;
}

static __device__ __forceinline__ f32x4 mfma16(bf16x8 a, bf16x8 b, f32x4 c) {
    return __builtin_amdgcn_mfma_f32_16x16x32_bf16(a, b, c, 0, 0, 0);
}

// slice S = (jt = S>>3, ks = S&7) offset from per-lane base, in ELEMENTS
// (floats for X, shorts for Q; both have row stride 256 elements)
#define XGOFF(S) ((((S) >> 3) & 3) * 16384 + ((S) & 7) * 32)

// ---- prep kernels (r3 verbatim) ----
__global__ void qprep_u(const float* __restrict__ wt,
                        short* __restrict__ Ur, short* __restrict__ Ui) {
    int idx = blockIdx.x * 256 + threadIdx.x;
    float2 v = ((const float2*)wt)[idx];
    Ur[idx] = f2bf(v.x);
    Ui[idx] = f2bf(v.y);
}

__global__ void qprep_ps(const float* __restrict__ rw, const float* __restrict__ lm,
                         float* __restrict__ pv, float* __restrict__ sv) {
    int t = threadIdx.x;
    float w0 = rw[t], w1 = rw[t + 64];
    float m = fmaxf(w0, w1);
    #pragma unroll
    for (int o = 32; o > 0; o >>= 1) m = fmaxf(m, __shfl_xor(m, o));
    float e0 = expf(w0 - m), e1 = expf(w1 - m);
    float ss = e0 + e1;
    #pragma unroll
    for (int o = 32; o > 0; o >>= 1) ss += __shfl_xor(ss, o);
    pv[t] = e0 / ss;
    pv[t + 64] = e1 / ss;
    if (t == 0) sv[0] = 1.f / (1.f + expf(-lm[0]));
}

__global__ void qprep_q(const float* __restrict__ wt,
                        short* __restrict__ Qrb, short* __restrict__ Qib) {
    int j = blockIdx.x;
    int k = threadIdx.x;
    float ar = 0.f, ai = 0.f;
    for (int i = 0; i < 128; ++i) {
        float2 uk = ((const float2*)wt)[i * 256 + k];
        float2 uj = ((const float2*)wt)[i * 256 + j];
        ar += uk.x * uj.x + uk.y * uj.y;
        ai += uk.x * uj.y - uk.y * uj.x;
    }
    Qrb[j * 256 + k] = f2bf(ar);
    Qib[j * 256 + k] = f2bf(ai);
}

// ---- pipeline phase macros (P is a LITERAL) ----
#define ISSUE_X(S, a, b, c, d) do {                                             \
    a = *(const f32x4*)(xgR + XGOFF(S));                                        \
    b = *(const f32x4*)(xgR + XGOFF(S) + 4);                                    \
    c = *(const f32x4*)(xgI + XGOFF(S));                                        \
    d = *(const f32x4*)(xgI + XGOFF(S) + 4);                                    \
} while (0)

#define PHASE(P, ga, gb, ia, ib, qrc, qic, qrn, qin) do {                       \
    bf16x8 axr = pack8(ga, gb);                                                 \
    bf16x8 axi = pack8(ia, ib);                                                 \
    if ((P) + 2 < 32) ISSUE_X((P) + 2, ga, gb, ia, ib);                         \
    if (dotr && ((P) + 1 < 32)) {                                               \
        qrn = *(const bf16x8*)(qbr + XGOFF((P) + 1));                           \
        qin = *(const bf16x8*)(qbi + XGOFF((P) + 1));                           \
    }                                                                           \
    __builtin_amdgcn_sched_barrier(0);  /* pin issued loads above MFMAs */      \
    bf16x8 axrn = axr ^ (short)0x8000;                                          \
    {                                                                           \
        const int kloc = kb + c16;                                              \
        const int uo = kloc * 512 + ((((P) & 7) * 64 + g4 * 16) ^ ((kloc & 7) << 4)); \
        bf16x8 bur = *(const bf16x8*)(smem + uo);                               \
        bf16x8 bui = *(const bf16x8*)(smem + 32768 + uo);                       \
        yR0 = mfma16(axr,  bur, yR0);                                           \
        yR0 = mfma16(axi,  bui, yR0);                                           \
        yI0 = mfma16(axi,  bur, yI0);                                           \
        yI0 = mfma16(axrn, bui, yI0);                                           \
    }                                                                           \
    {                                                                           \
        const int kloc = kb + 16 + c16;                                         \
        const int uo = kloc * 512 + ((((P) & 7) * 64 + g4 * 16) ^ ((kloc & 7) << 4)); \
        bf16x8 bur = *(const bf16x8*)(smem + uo);                               \
        bf16x8 bui = *(const bf16x8*)(smem + 32768 + uo);                       \
        yR1 = mfma16(axr,  bur, yR1);                                           \
        yR1 = mfma16(axi,  bui, yR1);                                           \
        yI1 = mfma16(axi,  bur, yI1);                                           \
        yI1 = mfma16(axrn, bui, yI1);                                           \
    }                                                                           \
    if (dotr) {                                                                 \
        bf16x8 axin = axi ^ (short)0x8000;                                      \
        tr4 = mfma16(axr,  qrc, tr4);                                           \
        tr4 = mfma16(axin, qic, tr4);                                           \
    }                                                                           \
} while (0)

#define PH_E(P) PHASE(P, gA0, gA1, gA2, gA3, qr0, qi0, qr1, qi1)
#define PH_O(P) PHASE(P, gB0, gB1, gB2, gB3, qr1, qi1, qr0, qi0)

// ---- stage B for one jt (all-scalar accumulators) ----
#define STAGEB_KS(JT, KS2) do {                                                 \
    const int ib0 = wm * 32 + c16;                                              \
    const int ib1 = wm * 32 + 16 + c16;                                         \
    bf16x8 aur0 = *(const bf16x8*)(Urg + (size_t)ib0 * 256 + (JT) * 64 + (KS2) * 32 + g4 * 8); \
    bf16x8 aui0 = *(const bf16x8*)(Uig + (size_t)ib0 * 256 + (JT) * 64 + (KS2) * 32 + g4 * 8); \
    bf16x8 aur1 = *(const bf16x8*)(Urg + (size_t)ib1 * 256 + (JT) * 64 + (KS2) * 32 + g4 * 8); \
    bf16x8 aui1 = *(const bf16x8*)(Uig + (size_t)ib1 * 256 + (JT) * 64 + (KS2) * 32 + g4 * 8); \
    bf16x8 auin0 = aui0 ^ (short)0x8000;                                        \
    bf16x8 auin1 = aui1 ^ (short)0x8000;                                        \
    {                                                                           \
        const int kloc = wn * 32 + c16;                                         \
        const int off  = kloc * 128 + (((KS2) * 64 + g4 * 16) ^ ((kloc & 7) << 4)); \
        bf16x8 byr = *(const bf16x8*)(smem + 65536 + off);                      \
        bf16x8 byi = *(const bf16x8*)(smem + 73728 + off);                      \
        sR00 = mfma16(aur0,  byr, sR00); sR00 = mfma16(auin0, byi, sR00);       \
        sI00 = mfma16(aui0,  byr, sI00); sI00 = mfma16(aur0,  byi, sI00);       \
        sR10 = mfma16(aur1,  byr, sR10); sR10 = mfma16(auin1, byi, sR10);       \
        sI10 = mfma16(aui1,  byr, sI10); sI10 = mfma16(aur1,  byi, sI10);       \
    }                                                                           \
    {                                                                           \
        const int kloc = wn * 32 + 16 + c16;                                    \
        const int off  = kloc * 128 + (((KS2) * 64 + g4 * 16) ^ ((kloc & 7) << 4)); \
        bf16x8 byr = *(const bf16x8*)(smem + 65536 + off);                      \
        bf16x8 byi = *(const bf16x8*)(smem + 73728 + off);                      \
        sR01 = mfma16(aur0,  byr, sR01); sR01 = mfma16(auin0, byi, sR01);       \
        sI01 = mfma16(aui0,  byr, sI01); sI01 = mfma16(aur0,  byi, sI01);       \
        sR11 = mfma16(aur1,  byr, sR11); sR11 = mfma16(auin1, byi, sR11);       \
        sI11 = mfma16(aui1,  byr, sI11); sI11 = mfma16(aur1,  byi, sI11);       \
    }                                                                           \
} while (0)

// ---- Yt exchange + stage B ----
#define YT_AND_B(JT) do {                                                       \
    __builtin_amdgcn_s_barrier();          /* stageB(prev) reads done */        \
    __builtin_amdgcn_sched_barrier(0);                                          \
    {                                                                           \
        const int klA = kb + c16;                                               \
        const int oA  = klA * 128 + ((ja * 2 + g4 * 8) ^ ((klA & 7) << 4));     \
        uint2 v;                                                                \
        v.x = cvtpk2(yR0[0], yR0[1]); v.y = cvtpk2(yR0[2], yR0[3]);             \
        *(uint2*)(smem + 65536 + oA) = v;                                       \
        v.x = cvtpk2(yI0[0], yI0[1]); v.y = cvtpk2(yI0[2], yI0[3]);             \
        *(uint2*)(smem + 73728 + oA) = v;                                       \
        const int klB = kb + 16 + c16;                                          \
        const int oB  = klB * 128 + ((ja * 2 + g4 * 8) ^ ((klB & 7) << 4));     \
        v.x = cvtpk2(yR1[0], yR1[1]); v.y = cvtpk2(yR1[2], yR1[3]);             \
        *(uint2*)(smem + 65536 + oB) = v;                                       \
        v.x = cvtpk2(yI1[0], yI1[1]); v.y = cvtpk2(yI1[2], yI1[3]);             \
        *(uint2*)(smem + 73728 + oB) = v;                                       \
    }                                                                           \
    asm volatile("s_waitcnt lgkmcnt(0)" ::: "memory");                          \
    __builtin_amdgcn_sched_barrier(0);                                          \
    __builtin_amdgcn_s_barrier();                                               \
    __builtin_amdgcn_sched_barrier(0);                                          \
    STAGEB_KS(JT, 0);                                                           \
    STAGEB_KS(JT, 1);                                                           \
    yR0 = zero; yR1 = zero; yI0 = zero; yI1 = zero;                             \
} while (0)

// ---- main fused kernel ----
__global__ __launch_bounds__(512, 2) void qfused(
    const float* __restrict__ xr, const float* __restrict__ xi,
    const short* __restrict__ Urg, const short* __restrict__ Uig,
    const short* __restrict__ Qrb, const short* __restrict__ Qib,
    const float* __restrict__ pv, const float* __restrict__ sv,
    float* __restrict__ out)
{
    // LDS: [0,65536) U-half swizzled (R 0, I 32768); [65536,81920) Yt (R/I).
    __shared__ __align__(16) char smem[81920];

    const int bx   = blockIdx.x;
    const int b    = bx >> 1;
    const int kh   = bx & 1;
    const int tid  = threadIdx.x;
    const int lane = tid & 63;
    const int w    = tid >> 6;
    const int c16  = lane & 15;
    const int g4   = lane >> 4;

    // ---- stage U-half into swizzled LDS (r3-proven) ----
    #pragma unroll
    for (int q = 0; q < 4; ++q) {
        int c    = tid + q * 512;
        int row  = c >> 5;
        int slot = c & 31;
        int ss   = slot ^ (row & 7);
        const short* sr = Urg + (size_t)(kh * 64 + row) * 256 + ss * 8;
        const short* si = Uig + (size_t)(kh * 64 + row) * 256 + ss * 8;
        *(bf16x8*)(smem + row * 512 + slot * 16)         = *(const bf16x8*)sr;
        *(bf16x8*)(smem + 32768 + row * 512 + slot * 16) = *(const bf16x8*)si;
    }

    const float* xrb = xr + ((size_t)b << 16);
    const float* xib = xi + ((size_t)b << 16);

    const int  ja   = (w & 3) * 16;      // stage-A j-group
    const int  kb   = (w >> 2) * 32;     // stage-A k'-group
    const int  wm   = w >> 1;            // stage-B i-quarter
    const int  wn   = w & 1;             // stage-B k'-half-of-half
    const bool dotr = (w < 4);

    // per-lane X/Q base (fragment order: row ja+c16, k chunk g4*8)
    const float* xgR = xrb + (size_t)(ja + c16) * 256 + g4 * 8;
    const float* xgI = xib + (size_t)(ja + c16) * 256 + g4 * 8;
    const short* qbr = Qrb + (size_t)(ja + c16) * 256 + g4 * 8;
    const short* qbi = Qib + (size_t)(ja + c16) * 256 + g4 * 8;

    f32x4 zero = {0.f, 0.f, 0.f, 0.f};
    f32x4 sR00 = zero, sR01 = zero, sR10 = zero, sR11 = zero;
    f32x4 sI00 = zero, sI01 = zero, sI10 = zero, sI11 = zero;
    f32x4 tr4 = zero;
    f32x4 yR0 = zero, yR1 = zero, yI0 = zero, yI1 = zero;

    f32x4 gA0, gA1, gA2, gA3;            // X ring slot A (even slices)
    f32x4 gB0, gB1, gB2, gB3;            // X ring slot B (odd slices)
    bf16x8 qr0 = {}, qi0 = {}, qr1 = {}, qi1 = {};

    // ---- prologue: issue slices 0,1 + Q slice 0; wait U staging; barrier ----
    ISSUE_X(0, gA0, gA1, gA2, gA3);
    ISSUE_X(1, gB0, gB1, gB2, gB3);
    if (dotr) {
        qr0 = *(const bf16x8*)(qbr + XGOFF(0));
        qi0 = *(const bf16x8*)(qbi + XGOFF(0));
    }
    asm volatile("s_waitcnt lgkmcnt(0)" ::: "memory");   // U ds_writes done
    __builtin_amdgcn_sched_barrier(0);
    __builtin_amdgcn_s_barrier();                        // vmcnt stays counted
    __builtin_amdgcn_sched_barrier(0);

    PH_E(0);  PH_O(1);  PH_E(2);  PH_O(3);  PH_E(4);  PH_O(5);  PH_E(6);  PH_O(7);
    YT_AND_B(0);
    PH_E(8);  PH_O(9);  PH_E(10); PH_O(11); PH_E(12); PH_O(13); PH_E(14); PH_O(15);
    YT_AND_B(1);
    PH_E(16); PH_O(17); PH_E(18); PH_O(19); PH_E(20); PH_O(21); PH_E(22); PH_O(23);
    YT_AND_B(2);
    PH_E(24); PH_O(25); PH_E(26); PH_O(27); PH_E(28); PH_O(29); PH_E(30); PH_O(31);
    YT_AND_B(3);

    // ---- trace: extract diag of tr4, reduce over block ----
    float loc = (dotr && ((c16 >> 2) == g4)) ? tr4[c16 & 3] : 0.f;
    #pragma unroll
    for (int o = 32; o > 0; o >>= 1) loc += __shfl_xor(loc, o);
    __syncthreads();                      // Yt dead; reuse for reduction
    float* red = (float*)(smem + 65536);
    if (lane == 0) red[w] = loc;
    __syncthreads();
    float tr = red[0] + red[1] + red[2] + red[3] + red[4] + red[5] + red[6] + red[7];

    float s     = sv[0];
    float inv   = s / tr;
    float onems = 1.f - s;
    float* outr = out + (size_t)b * 16384;
    float* outi = out + 8388608 + (size_t)b * 16384;

    #define EPI(SRV, SIV, MT, NT) do {                                          \
        int colc = kh * 64 + wn * 32 + (NT) * 16 + c16;                         \
        _Pragma("unroll")                                                       \
        for (int r = 0; r < 4; ++r) {                                           \
            int row = wm * 32 + (MT) * 16 + g4 * 4 + r;                         \
            float vr = SRV[r] * inv;                                            \
            if (row == colc) vr += onems * pv[row];                             \
            outr[row * 128 + colc] = vr;                                        \
            outi[row * 128 + colc] = SIV[r] * inv;                              \
        }                                                                       \
    } while (0)

    EPI(sR00, sI00, 0, 0);
    EPI(sR01, sI01, 0, 1);
    EPI(sR10, sI10, 1, 0);
    EPI(sR11, sI11, 1, 1);
    #undef EPI
}

extern "C" void kernel_launch(void* const* d_in, const int* in_sizes, int n_in,
                              void* d_out, int out_size, void* d_ws, size_t ws_size,
                              hipStream_t stream) {
    (void)in_sizes; (void)n_in; (void)out_size; (void)ws_size;
    const float* xr = (const float*)d_in[0];
    const float* xi = (const float*)d_in[1];
    const float* wt = (const float*)d_in[2];
    const float* rw = (const float*)d_in[3];
    const float* lm = (const float*)d_in[4];

    short* Ur  = (short*)d_ws;                        // 128x256 bf16 (64 KB)
    short* Ui  = Ur + 32768;                          // 64 KB
    float* pv  = (float*)((char*)d_ws + 131072);      // 128 f32
    float* sv  = pv + 128;                            // 1 f32
    short* Qrb = (short*)((char*)d_ws + 135168);      // 256x256 bf16 (128 KB)
    short* Qib = (short*)((char*)d_ws + 266240);      // 128 KB
    float* o   = (float*)d_out;

    qprep_u<<<dim3(128), dim3(256), 0, stream>>>(wt, Ur, Ui);
    qprep_ps<<<dim3(1), dim3(64), 0, stream>>>(rw, lm, pv, sv);
    qprep_q<<<dim3(256), dim3(256), 0, stream>>>(wt, Qrb, Qib);
    qfused<<<dim3(1024), dim3(512), 0, stream>>>(xr, xi, Ur, Ui, Qrb, Qib, pv, sv, o);
}